// Round 3
// baseline (1879.623 us; speedup 1.0000x reference)
//
#include <hip/hip_runtime.h>
#include <hip/hip_bf16.h>
#include <math.h>

#define DIMC 1024
#define NHEADS 16
#define HDIM 64
#define BATCH 4
#define SEQ 2048
#define NROWS (BATCH * SEQ)      // 8192
#define ATTN_SCALE 0.125f        // 64^-0.5

typedef __attribute__((ext_vector_type(8))) short short8;   // 8 bf16 = 4 VGPR
typedef __attribute__((ext_vector_type(4))) float f32x4;    // MFMA C/D

static __device__ __forceinline__ short f2bf(float f) {
    __hip_bfloat16 h = __float2bfloat16(f);
    return *reinterpret_cast<short*>(&h);
}

// ---------------------------------------------------------------------------
// transpose + fp32->bf16: src fp32 [1024][N] -> dst bf16 [N][1024]
// grid: (N/64, 1024/64), block 256
// ---------------------------------------------------------------------------
__global__ __launch_bounds__(256)
void transpose_cvt(const float* __restrict__ src, unsigned short* __restrict__ dst,
                   int N) {
    __shared__ float t[64][65];
    const int tid = threadIdx.x;
    const int cb = blockIdx.x * 64;   // col tile of src
    const int rb = blockIdx.y * 64;   // k tile (rows of src)
#pragma unroll
    for (int e = 0; e < 4; e++) {
        int idx = tid + e * 256;           // 0..1023
        int row = idx >> 4;
        int c4 = (idx & 15) << 2;
        *reinterpret_cast<float4*>(&t[row][c4]) =
            *reinterpret_cast<const float4*>(&src[(size_t)(rb + row) * N + cb + c4]);
    }
    __syncthreads();
#pragma unroll
    for (int e = 0; e < 2; e++) {
        int idx = tid + e * 256;           // 0..511
        int col = idx >> 3;                // 0..63
        int k8 = (idx & 7) << 3;           // 0..56
        short8 pk;
#pragma unroll
        for (int j = 0; j < 8; j++) pk[j] = f2bf(t[k8 + j][col]);
        *reinterpret_cast<short8*>(&dst[(size_t)(cb + col) * 1024 + rb + k8]) = pk;
    }
}

// ---------------------------------------------------------------------------
// bf16 MFMA GEMM core macro-parts: 128x128 tile, BK=32, 4 waves (2x2 of 64x64)
// LDS layout [kb][row][8] so ds_read_b128/ds_write_b128 are conflict-free.
// ---------------------------------------------------------------------------

// qkv: X fp32 [8192][1024] x Wt bf16 [3072][1024] -> scatter q/k/v fp32 [B,H,S,D]
__global__ __launch_bounds__(256)
void qkv_gemm_mfma(const float* __restrict__ X, const unsigned short* __restrict__ Wt,
                   float* __restrict__ qo, float* __restrict__ ko,
                   float* __restrict__ vo) {
    __shared__ short Alds[4][128][8];   // 8 KB
    __shared__ short Blds[4][128][8];   // 8 KB
    const int tid = threadIdx.x;
    const int lane = tid & 63;
    const int wave = tid >> 6;
    const int wr = wave >> 1, wc = wave & 1;
    const int rowbase = blockIdx.y * 128;
    const int colbase = blockIdx.x * 128;
    const int kb = lane >> 4, li = lane & 15;

    f32x4 acc[4][4];
#pragma unroll
    for (int m = 0; m < 4; m++)
#pragma unroll
        for (int n = 0; n < 4; n++) acc[m][n] = (f32x4){0.f, 0.f, 0.f, 0.f};

    for (int k0 = 0; k0 < DIMC; k0 += 32) {
#pragma unroll
        for (int e = 0; e < 2; e++) {
            int idx = tid + e * 256;       // 0..511
            int akb = idx & 3, row = idx >> 2;
            const float* s = &X[(size_t)(rowbase + row) * DIMC + k0 + akb * 8];
            float4 a0 = *reinterpret_cast<const float4*>(s);
            float4 a1 = *reinterpret_cast<const float4*>(s + 4);
            short8 w;
            w[0] = f2bf(a0.x); w[1] = f2bf(a0.y); w[2] = f2bf(a0.z); w[3] = f2bf(a0.w);
            w[4] = f2bf(a1.x); w[5] = f2bf(a1.y); w[6] = f2bf(a1.z); w[7] = f2bf(a1.w);
            *reinterpret_cast<short8*>(&Alds[akb][row][0]) = w;
            int bkb = akb, col = row;
            *reinterpret_cast<short8*>(&Blds[bkb][col][0]) =
                *reinterpret_cast<const short8*>(
                    &Wt[(size_t)(colbase + col) * 1024 + k0 + bkb * 8]);
        }
        __syncthreads();
        short8 af[4], bfr[4];
#pragma unroll
        for (int m = 0; m < 4; m++)
            af[m] = *reinterpret_cast<const short8*>(
                &Alds[kb][wr * 64 + m * 16 + li][0]);
#pragma unroll
        for (int n = 0; n < 4; n++)
            bfr[n] = *reinterpret_cast<const short8*>(
                &Blds[kb][wc * 64 + n * 16 + li][0]);
#pragma unroll
        for (int m = 0; m < 4; m++)
#pragma unroll
            for (int n = 0; n < 4; n++)
                acc[m][n] = __builtin_amdgcn_mfma_f32_16x16x32_bf16(
                    af[m], bfr[n], acc[m][n], 0, 0, 0);
        __syncthreads();
    }

    // epilogue: D row = token row, D col = qkv feature col
#pragma unroll
    for (int n = 0; n < 4; n++) {
        int col = colbase + wc * 64 + n * 16 + li;   // 0..3071
        int three = col >> 10;
        int cg = col & 1023;
        int h = cg >> 6, d = cg & 63;
        float* dst = (three == 0) ? qo : (three == 1) ? ko : vo;
        float mult = (three == 0) ? ATTN_SCALE : 1.0f;
#pragma unroll
        for (int m = 0; m < 4; m++) {
            int r0 = rowbase + wr * 64 + m * 16 + (lane >> 4) * 4;
#pragma unroll
            for (int r = 0; r < 4; r++) {
                int rowg = r0 + r;
                int b = rowg >> 11, s = rowg & 2047;
                dst[(((size_t)(b * NHEADS + h)) * SEQ + s) * HDIM + d] =
                    acc[m][n][r] * mult;
            }
        }
    }
}

// proj: Abf bf16 [8192][1024] x Wt bf16 [1024][1024] + bias -> out fp32 [8192][1024]
__global__ __launch_bounds__(256)
void proj_gemm_mfma(const unsigned short* __restrict__ Abf,
                    const unsigned short* __restrict__ Wt,
                    const float* __restrict__ bias, float* __restrict__ out) {
    __shared__ short Alds[4][128][8];
    __shared__ short Blds[4][128][8];
    const int tid = threadIdx.x;
    const int lane = tid & 63;
    const int wave = tid >> 6;
    const int wr = wave >> 1, wc = wave & 1;
    const int rowbase = blockIdx.y * 128;
    const int colbase = blockIdx.x * 128;
    const int kb = lane >> 4, li = lane & 15;

    f32x4 acc[4][4];
#pragma unroll
    for (int m = 0; m < 4; m++)
#pragma unroll
        for (int n = 0; n < 4; n++) acc[m][n] = (f32x4){0.f, 0.f, 0.f, 0.f};

    for (int k0 = 0; k0 < DIMC; k0 += 32) {
#pragma unroll
        for (int e = 0; e < 2; e++) {
            int idx = tid + e * 256;
            int akb = idx & 3, row = idx >> 2;
            *reinterpret_cast<short8*>(&Alds[akb][row][0]) =
                *reinterpret_cast<const short8*>(
                    &Abf[(size_t)(rowbase + row) * DIMC + k0 + akb * 8]);
            *reinterpret_cast<short8*>(&Blds[akb][row][0]) =
                *reinterpret_cast<const short8*>(
                    &Wt[(size_t)(colbase + row) * 1024 + k0 + akb * 8]);
        }
        __syncthreads();
        short8 af[4], bfr[4];
#pragma unroll
        for (int m = 0; m < 4; m++)
            af[m] = *reinterpret_cast<const short8*>(
                &Alds[kb][wr * 64 + m * 16 + li][0]);
#pragma unroll
        for (int n = 0; n < 4; n++)
            bfr[n] = *reinterpret_cast<const short8*>(
                &Blds[kb][wc * 64 + n * 16 + li][0]);
#pragma unroll
        for (int m = 0; m < 4; m++)
#pragma unroll
            for (int n = 0; n < 4; n++)
                acc[m][n] = __builtin_amdgcn_mfma_f32_16x16x32_bf16(
                    af[m], bfr[n], acc[m][n], 0, 0, 0);
        __syncthreads();
    }

#pragma unroll
    for (int n = 0; n < 4; n++) {
        int col = colbase + wc * 64 + n * 16 + li;
        float bv = bias[col];
#pragma unroll
        for (int m = 0; m < 4; m++) {
            int r0 = rowbase + wr * 64 + m * 16 + (lane >> 4) * 4;
#pragma unroll
            for (int r = 0; r < 4; r++)
                out[(size_t)(r0 + r) * DIMC + col] = acc[m][n][r] + bv;
        }
    }
}

// ---------------- flash attention (fp32, causal) — unchanged math, bf16 out ----
#define QBLK 256
#define KBLK 64

__global__ __launch_bounds__(256)
void flash_attn(const float* __restrict__ qg, const float* __restrict__ kg,
                const float* __restrict__ vg, unsigned short* __restrict__ og) {
    __shared__ float Ks[KBLK][HDIM];
    __shared__ float Vs[KBLK][HDIM];
    const int tid = threadIdx.x;
    const int qbase = blockIdx.x * QBLK;
    const int bh = blockIdx.y;
    const size_t head_off = (size_t)bh * SEQ * HDIM;
    const int sq = qbase + tid;

    float4 fq[16], fo[16];
    const float4* qrow =
        reinterpret_cast<const float4*>(qg + head_off + (size_t)sq * HDIM);
#pragma unroll
    for (int w = 0; w < 16; w++) {
        fq[w] = qrow[w];
        fo[w] = make_float4(0.f, 0.f, 0.f, 0.f);
    }
    float m = -1e30f, l = 0.f;

    const int ntiles = qbase / KBLK + QBLK / KBLK;
    for (int t = 0; t < ntiles; t++) {
        const int kbase = t * KBLK;
        __syncthreads();
#pragma unroll
        for (int e = 0; e < 4; e++) {
            int f4 = tid + e * 256;
            int r = f4 >> 4;
            int c4 = (f4 & 15) << 2;
            size_t src = head_off + (size_t)(kbase + r) * HDIM + c4;
            *reinterpret_cast<float4*>(&Ks[r][c4]) =
                *reinterpret_cast<const float4*>(&kg[src]);
            *reinterpret_cast<float4*>(&Vs[r][c4]) =
                *reinterpret_cast<const float4*>(&vg[src]);
        }
        __syncthreads();

        int kmax = sq - kbase + 1;
        if (kmax > KBLK) kmax = KBLK;
        for (int kk = 0; kk < kmax; kk++) {
            const float4* krow = reinterpret_cast<const float4*>(&Ks[kk][0]);
            float s = 0.f;
#pragma unroll
            for (int w = 0; w < 16; w++) {
                float4 kv = krow[w];
                s = fmaf(fq[w].x, kv.x, s);
                s = fmaf(fq[w].y, kv.y, s);
                s = fmaf(fq[w].z, kv.z, s);
                s = fmaf(fq[w].w, kv.w, s);
            }
            if (s > m) {
                float corr = __expf(m - s);
                m = s;
                l *= corr;
#pragma unroll
                for (int w = 0; w < 16; w++) {
                    fo[w].x *= corr; fo[w].y *= corr;
                    fo[w].z *= corr; fo[w].w *= corr;
                }
            }
            float p = __expf(s - m);
            l += p;
            const float4* vrow = reinterpret_cast<const float4*>(&Vs[kk][0]);
#pragma unroll
            for (int w = 0; w < 16; w++) {
                float4 vv = vrow[w];
                fo[w].x = fmaf(p, vv.x, fo[w].x);
                fo[w].y = fmaf(p, vv.y, fo[w].y);
                fo[w].z = fmaf(p, vv.z, fo[w].z);
                fo[w].w = fmaf(p, vv.w, fo[w].w);
            }
        }
    }

    const float inv = 1.f / l;
    const int b = bh / NHEADS, h = bh % NHEADS;
    unsigned short* orow = og + ((size_t)(b * SEQ + sq)) * DIMC + h * HDIM;
#pragma unroll
    for (int w = 0; w < 8; w++) {
        float4 u = fo[2 * w], v2 = fo[2 * w + 1];
        short8 pk;
        pk[0] = f2bf(u.x * inv);  pk[1] = f2bf(u.y * inv);
        pk[2] = f2bf(u.z * inv);  pk[3] = f2bf(u.w * inv);
        pk[4] = f2bf(v2.x * inv); pk[5] = f2bf(v2.y * inv);
        pk[6] = f2bf(v2.z * inv); pk[7] = f2bf(v2.w * inv);
        *reinterpret_cast<short8*>(&orow[w * 8]) = pk;
    }
}

extern "C" void kernel_launch(void* const* d_in, const int* in_sizes, int n_in,
                              void* d_out, int out_size, void* d_ws, size_t ws_size,
                              hipStream_t stream) {
    const float* x      = (const float*)d_in[0];   // [4,2048,1024]
    const float* w_qkv  = (const float*)d_in[1];   // [1024,3072]
    const float* w_proj = (const float*)d_in[2];   // [1024,1024]
    const float* b_proj = (const float*)d_in[3];   // [1024]
    float* out = (float*)d_out;                    // [4,2048,1024] fp32

    char* w = (char*)d_ws;
    float* qb  = (float*)(w);                          // 32 MB fp32 [B,H,S,D]
    float* kb  = (float*)(w + ((size_t)32 << 20));     // 32 MB
    float* vb  = (float*)(w + ((size_t)64 << 20));     // 32 MB
    unsigned short* ao  = (unsigned short*)(w + ((size_t)96 << 20));   // 16 MB bf16 [8192][1024]
    unsigned short* wqt = (unsigned short*)(w + ((size_t)112 << 20));  // 6 MB bf16 [3072][1024]
    unsigned short* wpt = (unsigned short*)(w + ((size_t)118 << 20));  // 2 MB bf16 [1024][1024]

    // 0) weight transpose + bf16 convert (idempotent, reruns every call)
    transpose_cvt<<<dim3(3 * DIMC / 64, DIMC / 64), 256, 0, stream>>>(w_qkv, wqt, 3 * DIMC);
    transpose_cvt<<<dim3(DIMC / 64, DIMC / 64), 256, 0, stream>>>(w_proj, wpt, DIMC);
    // 1) QKV projection (bf16 MFMA) + scatter (q pre-scaled)
    qkv_gemm_mfma<<<dim3(3 * DIMC / 128, NROWS / 128), 256, 0, stream>>>(x, wqt, qb, kb, vb);
    // 2) causal flash attention (fp32), writes bf16
    flash_attn<<<dim3(SEQ / QBLK, BATCH * NHEADS), 256, 0, stream>>>(qb, kb, vb, ao);
    // 3) output projection (bf16 MFMA) + bias
    proj_gemm_mfma<<<dim3(DIMC / 128, NROWS / 128), 256, 0, stream>>>(ao, wpt, b_proj, out);
}

// Round 4
// 381.969 us; speedup vs baseline: 4.9209x; 4.9209x over previous
//
#include <hip/hip_runtime.h>
#include <hip/hip_bf16.h>
#include <math.h>

#define DIMC 1024
#define NHEADS 16
#define HDIM 64
#define BATCH 4
#define SEQ 2048
#define NROWS (BATCH * SEQ)      // 8192
#define ATTN_SCALE 0.125f        // 64^-0.5

typedef __attribute__((ext_vector_type(8))) short short8;   // 8 bf16 = 4 VGPR
typedef __attribute__((ext_vector_type(4))) short short4v;  // 4 bf16 = 2 VGPR
typedef __attribute__((ext_vector_type(4))) float f32x4;    // MFMA C/D

static __device__ __forceinline__ short f2bf(float f) {
    __hip_bfloat16 h = __float2bfloat16(f);
    return *reinterpret_cast<short*>(&h);
}

// ---------------------------------------------------------------------------
// transpose + fp32->bf16: src fp32 [1024][N] -> dst bf16 [N][1024]
// ---------------------------------------------------------------------------
__global__ __launch_bounds__(256)
void transpose_cvt(const float* __restrict__ src, unsigned short* __restrict__ dst,
                   int N) {
    __shared__ float t[64][65];
    const int tid = threadIdx.x;
    const int cb = blockIdx.x * 64;
    const int rb = blockIdx.y * 64;
#pragma unroll
    for (int e = 0; e < 4; e++) {
        int idx = tid + e * 256;
        int row = idx >> 4;
        int c4 = (idx & 15) << 2;
        *reinterpret_cast<float4*>(&t[row][c4]) =
            *reinterpret_cast<const float4*>(&src[(size_t)(rb + row) * N + cb + c4]);
    }
    __syncthreads();
#pragma unroll
    for (int e = 0; e < 2; e++) {
        int idx = tid + e * 256;
        int col = idx >> 3;
        int k8 = (idx & 7) << 3;
        short8 pk;
#pragma unroll
        for (int j = 0; j < 8; j++) pk[j] = f2bf(t[k8 + j][col]);
        *reinterpret_cast<short8*>(&dst[(size_t)(cb + col) * 1024 + rb + k8]) = pk;
    }
}

// ---------------------------------------------------------------------------
// qkv: X fp32 [8192][1024] x Wt bf16 [3072][1024] -> bf16 q,k [B,H,S,D], vt [B,H,D,S]
// q pre-scaled by ATTN_SCALE
// ---------------------------------------------------------------------------
__global__ __launch_bounds__(256)
void qkv_gemm_mfma(const float* __restrict__ X, const unsigned short* __restrict__ Wt,
                   unsigned short* __restrict__ qo, unsigned short* __restrict__ ko,
                   unsigned short* __restrict__ vt) {
    __shared__ short Alds[4][128][8];
    __shared__ short Blds[4][128][8];
    const int tid = threadIdx.x;
    const int lane = tid & 63;
    const int wave = tid >> 6;
    const int wr = wave >> 1, wc = wave & 1;
    const int rowbase = blockIdx.y * 128;
    const int colbase = blockIdx.x * 128;
    const int kb = lane >> 4, li = lane & 15, g = lane >> 4;

    f32x4 acc[4][4];
#pragma unroll
    for (int m = 0; m < 4; m++)
#pragma unroll
        for (int n = 0; n < 4; n++) acc[m][n] = (f32x4){0.f, 0.f, 0.f, 0.f};

    for (int k0 = 0; k0 < DIMC; k0 += 32) {
#pragma unroll
        for (int e = 0; e < 2; e++) {
            int idx = tid + e * 256;
            int akb = idx & 3, row = idx >> 2;
            const float* s = &X[(size_t)(rowbase + row) * DIMC + k0 + akb * 8];
            float4 a0 = *reinterpret_cast<const float4*>(s);
            float4 a1 = *reinterpret_cast<const float4*>(s + 4);
            short8 w;
            w[0] = f2bf(a0.x); w[1] = f2bf(a0.y); w[2] = f2bf(a0.z); w[3] = f2bf(a0.w);
            w[4] = f2bf(a1.x); w[5] = f2bf(a1.y); w[6] = f2bf(a1.z); w[7] = f2bf(a1.w);
            *reinterpret_cast<short8*>(&Alds[akb][row][0]) = w;
            *reinterpret_cast<short8*>(&Blds[akb][row][0]) =
                *reinterpret_cast<const short8*>(
                    &Wt[(size_t)(colbase + row) * 1024 + k0 + akb * 8]);
        }
        __syncthreads();
        short8 af[4], bfr[4];
#pragma unroll
        for (int m = 0; m < 4; m++)
            af[m] = *reinterpret_cast<const short8*>(
                &Alds[kb][wr * 64 + m * 16 + li][0]);
#pragma unroll
        for (int n = 0; n < 4; n++)
            bfr[n] = *reinterpret_cast<const short8*>(
                &Blds[kb][wc * 64 + n * 16 + li][0]);
#pragma unroll
        for (int m = 0; m < 4; m++)
#pragma unroll
            for (int n = 0; n < 4; n++)
                acc[m][n] = __builtin_amdgcn_mfma_f32_16x16x32_bf16(
                    af[m], bfr[n], acc[m][n], 0, 0, 0);
        __syncthreads();
    }

    // epilogue: col0 is 64-aligned -> whole wave-col range is one head, one of q/k/v
    const int col0 = colbase + wc * 64;
    const int three = col0 >> 10;
    const int h = (col0 & 1023) >> 6;
    if (three < 2) {
        unsigned short* dst = (three == 0) ? qo : ko;
        const float mult = (three == 0) ? ATTN_SCALE : 1.0f;
#pragma unroll
        for (int n = 0; n < 4; n++) {
            int d = n * 16 + li;
#pragma unroll
            for (int m = 0; m < 4; m++) {
                int r0 = rowbase + wr * 64 + m * 16 + g * 4;
                int b = r0 >> 11;
                size_t base = ((size_t)(b * NHEADS + h) * SEQ) * HDIM + d;
#pragma unroll
                for (int r = 0; r < 4; r++) {
                    int s = (r0 + r) & 2047;
                    dst[base + (size_t)s * HDIM] = (unsigned short)f2bf(acc[m][n][r] * mult);
                }
            }
        }
    } else {
        // v: store transposed [B,H,D,S]; s-dim consecutive -> 8B packed stores
#pragma unroll
        for (int n = 0; n < 4; n++) {
            int d = n * 16 + li;
#pragma unroll
            for (int m = 0; m < 4; m++) {
                int r0 = rowbase + wr * 64 + m * 16 + g * 4;
                int b = r0 >> 11, s0 = r0 & 2047;
                short4v pk;
#pragma unroll
                for (int r = 0; r < 4; r++) pk[r] = f2bf(acc[m][n][r]);
                *reinterpret_cast<short4v*>(
                    &vt[((size_t)(b * NHEADS + h) * HDIM + d) * SEQ + s0]) = pk;
            }
        }
    }
}

// ---------------------------------------------------------------------------
// proj: Abf bf16 [8192][1024] x Wt bf16 [1024][1024] + bias -> out fp32
// ---------------------------------------------------------------------------
__global__ __launch_bounds__(256)
void proj_gemm_mfma(const unsigned short* __restrict__ Abf,
                    const unsigned short* __restrict__ Wt,
                    const float* __restrict__ bias, float* __restrict__ out) {
    __shared__ short Alds[4][128][8];
    __shared__ short Blds[4][128][8];
    const int tid = threadIdx.x;
    const int lane = tid & 63;
    const int wave = tid >> 6;
    const int wr = wave >> 1, wc = wave & 1;
    const int rowbase = blockIdx.y * 128;
    const int colbase = blockIdx.x * 128;
    const int kb = lane >> 4, li = lane & 15;

    f32x4 acc[4][4];
#pragma unroll
    for (int m = 0; m < 4; m++)
#pragma unroll
        for (int n = 0; n < 4; n++) acc[m][n] = (f32x4){0.f, 0.f, 0.f, 0.f};

    for (int k0 = 0; k0 < DIMC; k0 += 32) {
#pragma unroll
        for (int e = 0; e < 2; e++) {
            int idx = tid + e * 256;
            int akb = idx & 3, row = idx >> 2;
            *reinterpret_cast<short8*>(&Alds[akb][row][0]) =
                *reinterpret_cast<const short8*>(
                    &Abf[(size_t)(rowbase + row) * DIMC + k0 + akb * 8]);
            *reinterpret_cast<short8*>(&Blds[akb][row][0]) =
                *reinterpret_cast<const short8*>(
                    &Wt[(size_t)(colbase + row) * 1024 + k0 + akb * 8]);
        }
        __syncthreads();
        short8 af[4], bfr[4];
#pragma unroll
        for (int m = 0; m < 4; m++)
            af[m] = *reinterpret_cast<const short8*>(
                &Alds[kb][wr * 64 + m * 16 + li][0]);
#pragma unroll
        for (int n = 0; n < 4; n++)
            bfr[n] = *reinterpret_cast<const short8*>(
                &Blds[kb][wc * 64 + n * 16 + li][0]);
#pragma unroll
        for (int m = 0; m < 4; m++)
#pragma unroll
            for (int n = 0; n < 4; n++)
                acc[m][n] = __builtin_amdgcn_mfma_f32_16x16x32_bf16(
                    af[m], bfr[n], acc[m][n], 0, 0, 0);
        __syncthreads();
    }

#pragma unroll
    for (int n = 0; n < 4; n++) {
        int col = colbase + wc * 64 + n * 16 + li;
        float bv = bias[col];
#pragma unroll
        for (int m = 0; m < 4; m++) {
            int r0 = rowbase + wr * 64 + m * 16 + (lane >> 4) * 4;
#pragma unroll
            for (int r = 0; r < 4; r++)
                out[(size_t)(r0 + r) * DIMC + col] = acc[m][n][r] + bv;
        }
    }
}

// ---------------------------------------------------------------------------
// MFMA flash attention (causal). 4 waves x 32 q-rows, KV tiles of 64.
// Swapped QK^T: S^T = K·Q^T  (D[kv][q]: kv=16m+4g+r, q=li+16n)
// PV as O^T = V^T·P^T        (D[d][q]:  d=16df+4g+r, q=li+16n)
// q,k bf16 [BH,S,64]; vt bf16 [BH,64,S]; og bf16 [8192][1024]
// ---------------------------------------------------------------------------
__global__ __launch_bounds__(256)
void flash_attn_mfma(const unsigned short* __restrict__ qg,
                     const unsigned short* __restrict__ kg,
                     const unsigned short* __restrict__ vt,
                     unsigned short* __restrict__ og) {
    __shared__ short Klds[8][64][8];      // [dblk][kv][8d]   8KB
    __shared__ short Vlds[8][64][8];      // [kvblk][d][8kv]  8KB
    __shared__ short Plds[4][8][32][8];   // per-wave [kvblk][q][8kv] 16KB
    const int tid = threadIdx.x;
    const int lane = tid & 63;
    const int w = tid >> 6;
    const int g = lane >> 4, li = lane & 15;
    const int bh = blockIdx.y;
    const int qbase = blockIdx.x * 128;
    const int qw = qbase + w * 32;
    const size_t head = (size_t)bh * SEQ * HDIM;   // q,k and vt have same head stride

    // Q fragments (B-operand of swapped QK^T): col q=li+16n, k d=32*ds+8g+j
    short8 bq[2][2];
#pragma unroll
    for (int n = 0; n < 2; n++)
#pragma unroll
        for (int ds = 0; ds < 2; ds++)
            bq[n][ds] = *reinterpret_cast<const short8*>(
                &qg[head + (size_t)(qw + li + 16 * n) * HDIM + ds * 32 + g * 8]);

    f32x4 accO[4][2];                    // [df][n]
#pragma unroll
    for (int df = 0; df < 4; df++)
#pragma unroll
        for (int n = 0; n < 2; n++) accO[df][n] = (f32x4){0.f, 0.f, 0.f, 0.f};
    float mrow[2] = {-INFINITY, -INFINITY};
    float lrow[2] = {0.f, 0.f};

    const int ntiles = qbase / 64 + 2;
    for (int t = 0; t < ntiles; t++) {
        const int kvbase = t * 64;
        __syncthreads();
#pragma unroll
        for (int e = 0; e < 2; e++) {
            int c = tid + e * 256;       // 0..511
            int r = c & 63, blk = c >> 6;
            *reinterpret_cast<short8*>(&Klds[blk][r][0]) =
                *reinterpret_cast<const short8*>(
                    &kg[head + (size_t)(kvbase + r) * HDIM + blk * 8]);
            *reinterpret_cast<short8*>(&Vlds[blk][r][0]) =
                *reinterpret_cast<const short8*>(
                    &vt[head + (size_t)r * SEQ + kvbase + blk * 8]);
        }
        __syncthreads();

        if (kvbase <= qw + 31) {         // wave-uniform causal skip
            // ---- S^T = K·Q^T ----
            f32x4 s[4][2];
#pragma unroll
            for (int m = 0; m < 4; m++)
#pragma unroll
                for (int n = 0; n < 2; n++) s[m][n] = (f32x4){0.f, 0.f, 0.f, 0.f};
#pragma unroll
            for (int ds = 0; ds < 2; ds++) {
                short8 ak[4];
#pragma unroll
                for (int m = 0; m < 4; m++)
                    ak[m] = *reinterpret_cast<const short8*>(
                        &Klds[ds * 4 + g][li + 16 * m][0]);
#pragma unroll
                for (int m = 0; m < 4; m++)
#pragma unroll
                    for (int n = 0; n < 2; n++)
                        s[m][n] = __builtin_amdgcn_mfma_f32_16x16x32_bf16(
                            ak[m], bq[n][ds], s[m][n], 0, 0, 0);
            }
            // ---- mask (diagonal tiles only) + tile max ----
            const bool diag = (kvbase + 63 > qw);
            float tmax[2] = {-INFINITY, -INFINITY};
#pragma unroll
            for (int n = 0; n < 2; n++) {
                int q = qw + li + 16 * n;
#pragma unroll
                for (int m = 0; m < 4; m++) {
#pragma unroll
                    for (int r = 0; r < 4; r++) {
                        if (diag) {
                            int kv = kvbase + 16 * m + 4 * g + r;
                            if (kv > q) s[m][n][r] = -INFINITY;
                        }
                        tmax[n] = fmaxf(tmax[n], s[m][n][r]);
                    }
                }
            }
#pragma unroll
            for (int n = 0; n < 2; n++) {
                tmax[n] = fmaxf(tmax[n], __shfl_xor(tmax[n], 16));
                tmax[n] = fmaxf(tmax[n], __shfl_xor(tmax[n], 32));
            }
            float corr[2];
#pragma unroll
            for (int n = 0; n < 2; n++) {
                float mnew = fmaxf(mrow[n], tmax[n]);
                corr[n] = __expf(mrow[n] - mnew);   // -inf first time -> 0
                mrow[n] = mnew;
            }
            // ---- P = exp(S-m), pack P^T to LDS, row sums ----
            float tsum[2] = {0.f, 0.f};
#pragma unroll
            for (int m = 0; m < 4; m++) {
#pragma unroll
                for (int n = 0; n < 2; n++) {
                    float p0 = __expf(s[m][n][0] - mrow[n]);
                    float p1 = __expf(s[m][n][1] - mrow[n]);
                    float p2 = __expf(s[m][n][2] - mrow[n]);
                    float p3 = __expf(s[m][n][3] - mrow[n]);
                    tsum[n] += (p0 + p1) + (p2 + p3);
                    short4v pk;
                    pk[0] = f2bf(p0); pk[1] = f2bf(p1);
                    pk[2] = f2bf(p2); pk[3] = f2bf(p3);
                    *reinterpret_cast<short4v*>(
                        &Plds[w][2 * m + (g >> 1)][li + 16 * n][(g & 1) * 4]) = pk;
                }
            }
#pragma unroll
            for (int n = 0; n < 2; n++) {
                tsum[n] += __shfl_xor(tsum[n], 16);
                tsum[n] += __shfl_xor(tsum[n], 32);
                lrow[n] = lrow[n] * corr[n] + tsum[n];
            }
            // ---- rescale O ----
#pragma unroll
            for (int df = 0; df < 4; df++)
#pragma unroll
                for (int n = 0; n < 2; n++) {
                    accO[df][n][0] *= corr[n]; accO[df][n][1] *= corr[n];
                    accO[df][n][2] *= corr[n]; accO[df][n][3] *= corr[n];
                }
            // ---- O^T += V^T·P^T ----
#pragma unroll
            for (int ks = 0; ks < 2; ks++) {
                short8 av[4], bp[2];
#pragma unroll
                for (int df = 0; df < 4; df++)
                    av[df] = *reinterpret_cast<const short8*>(
                        &Vlds[ks * 4 + g][li + 16 * df][0]);
#pragma unroll
                for (int n = 0; n < 2; n++)
                    bp[n] = *reinterpret_cast<const short8*>(
                        &Plds[w][ks * 4 + g][li + 16 * n][0]);
#pragma unroll
                for (int df = 0; df < 4; df++)
#pragma unroll
                    for (int n = 0; n < 2; n++)
                        accO[df][n] = __builtin_amdgcn_mfma_f32_16x16x32_bf16(
                            av[df], bp[n], accO[df][n], 0, 0, 0);
            }
        }
    }

    // epilogue: O[q][d] = accO^T / l  -> og [b*SEQ+q][h*64+d], 8B packed (r->d)
    const int b = bh >> 4, h = bh & 15;
#pragma unroll
    for (int n = 0; n < 2; n++) {
        float inv = 1.0f / lrow[n];
        int q = qw + li + 16 * n;
        size_t rowoff = (size_t)(b * SEQ + q) * DIMC + h * HDIM;
#pragma unroll
        for (int df = 0; df < 4; df++) {
            short4v pk;
#pragma unroll
            for (int r = 0; r < 4; r++) pk[r] = f2bf(accO[df][n][r] * inv);
            *reinterpret_cast<short4v*>(&og[rowoff + 16 * df + 4 * g]) = pk;
        }
    }
}

extern "C" void kernel_launch(void* const* d_in, const int* in_sizes, int n_in,
                              void* d_out, int out_size, void* d_ws, size_t ws_size,
                              hipStream_t stream) {
    const float* x      = (const float*)d_in[0];   // [4,2048,1024]
    const float* w_qkv  = (const float*)d_in[1];   // [1024,3072]
    const float* w_proj = (const float*)d_in[2];   // [1024,1024]
    const float* b_proj = (const float*)d_in[3];   // [1024]
    float* out = (float*)d_out;                    // [4,2048,1024] fp32

    char* w = (char*)d_ws;
    unsigned short* qb  = (unsigned short*)(w);                        // 16 MB bf16 [B,H,S,D]
    unsigned short* kb  = (unsigned short*)(w + ((size_t)16 << 20));   // 16 MB bf16 [B,H,S,D]
    unsigned short* vtb = (unsigned short*)(w + ((size_t)32 << 20));   // 16 MB bf16 [B,H,D,S]
    unsigned short* ao  = (unsigned short*)(w + ((size_t)48 << 20));   // 16 MB bf16 [8192][1024]
    unsigned short* wqt = (unsigned short*)(w + ((size_t)64 << 20));   // 6 MB bf16 [3072][1024]
    unsigned short* wpt = (unsigned short*)(w + ((size_t)72 << 20));   // 2 MB bf16 [1024][1024]

    transpose_cvt<<<dim3(3 * DIMC / 64, DIMC / 64), 256, 0, stream>>>(w_qkv, wqt, 3 * DIMC);
    transpose_cvt<<<dim3(DIMC / 64, DIMC / 64), 256, 0, stream>>>(w_proj, wpt, DIMC);
    qkv_gemm_mfma<<<dim3(3 * DIMC / 128, NROWS / 128), 256, 0, stream>>>(x, wqt, qb, kb, vtb);
    flash_attn_mfma<<<dim3(SEQ / 128, BATCH * NHEADS), 256, 0, stream>>>(qb, kb, vtb, ao);
    proj_gemm_mfma<<<dim3(DIMC / 128, NROWS / 128), 256, 0, stream>>>(ao, wpt, b_proj, out);
}

// Round 5
// 306.910 us; speedup vs baseline: 6.1243x; 1.2446x over previous
//
#include <hip/hip_runtime.h>
#include <hip/hip_bf16.h>
#include <math.h>

#define DIMC 1024
#define NHEADS 16
#define HDIM 64
#define BATCH 4
#define SEQ 2048
#define NROWS (BATCH * SEQ)      // 8192
#define ATTN_SCALE 0.125f        // 64^-0.5
#define LOG2E 1.4426950408889634f

typedef __attribute__((ext_vector_type(8))) short short8;   // 8 bf16 = 4 VGPR
typedef __attribute__((ext_vector_type(4))) short short4v;  // 4 bf16 = 2 VGPR
typedef __attribute__((ext_vector_type(4))) float f32x4;    // MFMA C/D

static __device__ __forceinline__ short f2bf(float f) {
    __hip_bfloat16 h = __float2bfloat16(f);
    return *reinterpret_cast<short*>(&h);
}

// ---------------------------------------------------------------------------
// X fp32 -> bf16 (row-major copy), 8 elems/thread
// ---------------------------------------------------------------------------
__global__ __launch_bounds__(256)
void xcvt(const float* __restrict__ in, unsigned short* __restrict__ out) {
    int i = blockIdx.x * 256 + threadIdx.x;      // 1M threads, 8 floats each
    const float4* p = reinterpret_cast<const float4*>(in) + 2 * i;
    float4 a = p[0], b = p[1];
    short8 pk;
    pk[0] = f2bf(a.x); pk[1] = f2bf(a.y); pk[2] = f2bf(a.z); pk[3] = f2bf(a.w);
    pk[4] = f2bf(b.x); pk[5] = f2bf(b.y); pk[6] = f2bf(b.z); pk[7] = f2bf(b.w);
    reinterpret_cast<short8*>(out)[i] = pk;
}

// ---------------------------------------------------------------------------
// transpose + fp32->bf16: src fp32 [1024][N] -> dst bf16 [N][1024]
// ---------------------------------------------------------------------------
__global__ __launch_bounds__(256)
void transpose_cvt(const float* __restrict__ src, unsigned short* __restrict__ dst,
                   int N) {
    __shared__ float t[64][65];
    const int tid = threadIdx.x;
    const int cb = blockIdx.x * 64;
    const int rb = blockIdx.y * 64;
#pragma unroll
    for (int e = 0; e < 4; e++) {
        int idx = tid + e * 256;
        int row = idx >> 4;
        int c4 = (idx & 15) << 2;
        *reinterpret_cast<float4*>(&t[row][c4]) =
            *reinterpret_cast<const float4*>(&src[(size_t)(rb + row) * N + cb + c4]);
    }
    __syncthreads();
#pragma unroll
    for (int e = 0; e < 2; e++) {
        int idx = tid + e * 256;
        int col = idx >> 3;
        int k8 = (idx & 7) << 3;
        short8 pk;
#pragma unroll
        for (int j = 0; j < 8; j++) pk[j] = f2bf(t[k8 + j][col]);
        *reinterpret_cast<short8*>(&dst[(size_t)(cb + col) * 1024 + rb + k8]) = pk;
    }
}

// ---------------------------------------------------------------------------
// qkv: Xbf bf16 [8192][1024] x Wt bf16 [3072][1024] -> bf16 q,k [B,H,S,D], vt [B,H,D,S]
// q pre-scaled by ATTN_SCALE*LOG2E (softmax runs in exp2 domain)
// ---------------------------------------------------------------------------
__global__ __launch_bounds__(256)
void qkv_gemm_mfma(const unsigned short* __restrict__ Xbf,
                   const unsigned short* __restrict__ Wt,
                   unsigned short* __restrict__ qo, unsigned short* __restrict__ ko,
                   unsigned short* __restrict__ vt) {
    __shared__ short Alds[4][128][8];
    __shared__ short Blds[4][128][8];
    const int tid = threadIdx.x;
    const int lane = tid & 63;
    const int wave = tid >> 6;
    const int wr = wave >> 1, wc = wave & 1;
    const int rowbase = blockIdx.y * 128;
    const int colbase = blockIdx.x * 128;
    const int kb = lane >> 4, li = lane & 15, g = lane >> 4;

    f32x4 acc[4][4];
#pragma unroll
    for (int m = 0; m < 4; m++)
#pragma unroll
        for (int n = 0; n < 4; n++) acc[m][n] = (f32x4){0.f, 0.f, 0.f, 0.f};

    for (int k0 = 0; k0 < DIMC; k0 += 32) {
#pragma unroll
        for (int e = 0; e < 2; e++) {
            int idx = tid + e * 256;
            int akb = idx & 3, row = idx >> 2;
            *reinterpret_cast<short8*>(&Alds[akb][row][0]) =
                *reinterpret_cast<const short8*>(
                    &Xbf[(size_t)(rowbase + row) * DIMC + k0 + akb * 8]);
            *reinterpret_cast<short8*>(&Blds[akb][row][0]) =
                *reinterpret_cast<const short8*>(
                    &Wt[(size_t)(colbase + row) * 1024 + k0 + akb * 8]);
        }
        __syncthreads();
        short8 af[4], bfr[4];
#pragma unroll
        for (int m = 0; m < 4; m++)
            af[m] = *reinterpret_cast<const short8*>(
                &Alds[kb][wr * 64 + m * 16 + li][0]);
#pragma unroll
        for (int n = 0; n < 4; n++)
            bfr[n] = *reinterpret_cast<const short8*>(
                &Blds[kb][wc * 64 + n * 16 + li][0]);
#pragma unroll
        for (int m = 0; m < 4; m++)
#pragma unroll
            for (int n = 0; n < 4; n++)
                acc[m][n] = __builtin_amdgcn_mfma_f32_16x16x32_bf16(
                    af[m], bfr[n], acc[m][n], 0, 0, 0);
        __syncthreads();
    }

    const int col0 = colbase + wc * 64;
    const int three = col0 >> 10;
    const int h = (col0 & 1023) >> 6;
    if (three < 2) {
        unsigned short* dst = (three == 0) ? qo : ko;
        const float mult = (three == 0) ? (ATTN_SCALE * LOG2E) : 1.0f;
#pragma unroll
        for (int n = 0; n < 4; n++) {
            int d = n * 16 + li;
#pragma unroll
            for (int m = 0; m < 4; m++) {
                int r0 = rowbase + wr * 64 + m * 16 + g * 4;
                int b = r0 >> 11;
                size_t base = ((size_t)(b * NHEADS + h) * SEQ) * HDIM + d;
#pragma unroll
                for (int r = 0; r < 4; r++) {
                    int s = (r0 + r) & 2047;
                    dst[base + (size_t)s * HDIM] = (unsigned short)f2bf(acc[m][n][r] * mult);
                }
            }
        }
    } else {
        // v: store transposed [B,H,D,S]
#pragma unroll
        for (int n = 0; n < 4; n++) {
            int d = n * 16 + li;
#pragma unroll
            for (int m = 0; m < 4; m++) {
                int r0 = rowbase + wr * 64 + m * 16 + g * 4;
                int b = r0 >> 11, s0 = r0 & 2047;
                short4v pk;
#pragma unroll
                for (int r = 0; r < 4; r++) pk[r] = f2bf(acc[m][n][r]);
                *reinterpret_cast<short4v*>(
                    &vt[((size_t)(b * NHEADS + h) * HDIM + d) * SEQ + s0]) = pk;
            }
        }
    }
}

// ---------------------------------------------------------------------------
// proj: Abf bf16 [8192][1024] x Wt bf16 [1024][1024] + bias -> out fp32
// ---------------------------------------------------------------------------
__global__ __launch_bounds__(256)
void proj_gemm_mfma(const unsigned short* __restrict__ Abf,
                    const unsigned short* __restrict__ Wt,
                    const float* __restrict__ bias, float* __restrict__ out) {
    __shared__ short Alds[4][128][8];
    __shared__ short Blds[4][128][8];
    const int tid = threadIdx.x;
    const int lane = tid & 63;
    const int wave = tid >> 6;
    const int wr = wave >> 1, wc = wave & 1;
    const int rowbase = blockIdx.y * 128;
    const int colbase = blockIdx.x * 128;
    const int kb = lane >> 4, li = lane & 15;

    f32x4 acc[4][4];
#pragma unroll
    for (int m = 0; m < 4; m++)
#pragma unroll
        for (int n = 0; n < 4; n++) acc[m][n] = (f32x4){0.f, 0.f, 0.f, 0.f};

    for (int k0 = 0; k0 < DIMC; k0 += 32) {
#pragma unroll
        for (int e = 0; e < 2; e++) {
            int idx = tid + e * 256;
            int akb = idx & 3, row = idx >> 2;
            *reinterpret_cast<short8*>(&Alds[akb][row][0]) =
                *reinterpret_cast<const short8*>(
                    &Abf[(size_t)(rowbase + row) * DIMC + k0 + akb * 8]);
            *reinterpret_cast<short8*>(&Blds[akb][row][0]) =
                *reinterpret_cast<const short8*>(
                    &Wt[(size_t)(colbase + row) * 1024 + k0 + akb * 8]);
        }
        __syncthreads();
        short8 af[4], bfr[4];
#pragma unroll
        for (int m = 0; m < 4; m++)
            af[m] = *reinterpret_cast<const short8*>(
                &Alds[kb][wr * 64 + m * 16 + li][0]);
#pragma unroll
        for (int n = 0; n < 4; n++)
            bfr[n] = *reinterpret_cast<const short8*>(
                &Blds[kb][wc * 64 + n * 16 + li][0]);
#pragma unroll
        for (int m = 0; m < 4; m++)
#pragma unroll
            for (int n = 0; n < 4; n++)
                acc[m][n] = __builtin_amdgcn_mfma_f32_16x16x32_bf16(
                    af[m], bfr[n], acc[m][n], 0, 0, 0);
        __syncthreads();
    }

#pragma unroll
    for (int n = 0; n < 4; n++) {
        int col = colbase + wc * 64 + n * 16 + li;
        float bv = bias[col];
#pragma unroll
        for (int m = 0; m < 4; m++) {
            int r0 = rowbase + wr * 64 + m * 16 + (lane >> 4) * 4;
#pragma unroll
            for (int r = 0; r < 4; r++)
                out[(size_t)(r0 + r) * DIMC + col] = acc[m][n][r] + bv;
        }
    }
}

// ---------------------------------------------------------------------------
// MFMA flash attention (causal), exp2-domain softmax.
//  - coalesced K/V staging + XOR-swizzled LDS (chunk ^= row&7)
//  - double-buffered tiles, loads issued before compute (async split)
//  - balanced grid: block x handles q-tiles {x, 15-x}  (constant 34 tiles)
// q,k bf16 [BH,S,64] (q scaled by 0.125*log2e); vt bf16 [BH,64,S]; og bf16 [8192][1024]
// ---------------------------------------------------------------------------
__global__ __launch_bounds__(256)
void flash_attn_mfma(const unsigned short* __restrict__ qg,
                     const unsigned short* __restrict__ kg,
                     const unsigned short* __restrict__ vt,
                     unsigned short* __restrict__ og) {
    __shared__ short Klds[2][64][64];   // [buf][kv][d]  swizzled 16B chunks
    __shared__ short Vlds[2][64][64];   // [buf][d][kv]  swizzled
    __shared__ short Plds[4][32][64];   // [wave][q][kv] swizzled
    const int tid = threadIdx.x;
    const int lane = tid & 63;
    const int w = tid >> 6;
    const int g = lane >> 4, li = lane & 15;
    const int sw = li & 7;              // read-side swizzle key (row&7)
    const int bh = blockIdx.y;
    const size_t head = (size_t)bh * SEQ * HDIM;
    const int b = bh >> 4, h = bh & 15;

    // staging chunk coords (chunk index varies fastest along contiguous dim)
    const int c0r = tid >> 3, c0c = tid & 7;            // chunk 0
    const int c1r = (tid + 256) >> 3, c1c = tid & 7;    // chunk 1 (same cc)

    for (int pass = 0; pass < 2; pass++) {
        const int qtile = pass ? (15 - (int)blockIdx.x) : (int)blockIdx.x;
        const int qbase = qtile * 128;
        const int qw = qbase + w * 32;
        const int nt = 2 * qtile + 2;

        // Q fragments: col q=li+16n, k d=32*ds+8g+j
        short8 bq[2][2];
#pragma unroll
        for (int n = 0; n < 2; n++)
#pragma unroll
            for (int ds = 0; ds < 2; ds++)
                bq[n][ds] = *reinterpret_cast<const short8*>(
                    &qg[head + (size_t)(qw + li + 16 * n) * HDIM + ds * 32 + g * 8]);

        f32x4 accO[4][2];
#pragma unroll
        for (int df = 0; df < 4; df++)
#pragma unroll
            for (int n = 0; n < 2; n++) accO[df][n] = (f32x4){0.f, 0.f, 0.f, 0.f};
        float mrow[2] = {-INFINITY, -INFINITY};
        float lrow[2] = {0.f, 0.f};

        short8 kreg0, kreg1, vreg0, vreg1;
        // prologue: stage tile 0
        kreg0 = *reinterpret_cast<const short8*>(&kg[head + (size_t)c0r * HDIM + c0c * 8]);
        vreg0 = *reinterpret_cast<const short8*>(&vt[head + (size_t)c0r * SEQ + c0c * 8]);
        kreg1 = *reinterpret_cast<const short8*>(&kg[head + (size_t)c1r * HDIM + c1c * 8]);
        vreg1 = *reinterpret_cast<const short8*>(&vt[head + (size_t)c1r * SEQ + c1c * 8]);
        *reinterpret_cast<short8*>(&Klds[0][c0r][(c0c ^ (c0r & 7)) * 8]) = kreg0;
        *reinterpret_cast<short8*>(&Vlds[0][c0r][(c0c ^ (c0r & 7)) * 8]) = vreg0;
        *reinterpret_cast<short8*>(&Klds[0][c1r][(c1c ^ (c1r & 7)) * 8]) = kreg1;
        *reinterpret_cast<short8*>(&Vlds[0][c1r][(c1c ^ (c1r & 7)) * 8]) = vreg1;
        __syncthreads();

        for (int t = 0; t < nt; t++) {
            const int kvbase = t * 64;
            const int buf = t & 1;
            const bool more = (t + 1 < nt);
            if (more) {     // issue next-tile loads NOW; latency hides under compute
                const int kb2 = kvbase + 64;
                kreg0 = *reinterpret_cast<const short8*>(
                    &kg[head + (size_t)(kb2 + c0r) * HDIM + c0c * 8]);
                vreg0 = *reinterpret_cast<const short8*>(
                    &vt[head + (size_t)c0r * SEQ + kb2 + c0c * 8]);
                kreg1 = *reinterpret_cast<const short8*>(
                    &kg[head + (size_t)(kb2 + c1r) * HDIM + c1c * 8]);
                vreg1 = *reinterpret_cast<const short8*>(
                    &vt[head + (size_t)c1r * SEQ + kb2 + c1c * 8]);
            }

            if (kvbase <= qw + 31) {     // wave-uniform causal skip
                // ---- S^T = K·Q^T ----
                f32x4 s[4][2];
#pragma unroll
                for (int m = 0; m < 4; m++)
#pragma unroll
                    for (int n = 0; n < 2; n++) s[m][n] = (f32x4){0.f, 0.f, 0.f, 0.f};
#pragma unroll
                for (int ds = 0; ds < 2; ds++) {
                    short8 ak[4];
#pragma unroll
                    for (int m = 0; m < 4; m++)
                        ak[m] = *reinterpret_cast<const short8*>(
                            &Klds[buf][li + 16 * m][(((ds * 4 + g) ^ sw)) * 8]);
#pragma unroll
                    for (int m = 0; m < 4; m++)
#pragma unroll
                        for (int n = 0; n < 2; n++)
                            s[m][n] = __builtin_amdgcn_mfma_f32_16x16x32_bf16(
                                ak[m], bq[n][ds], s[m][n], 0, 0, 0);
                }
                // ---- mask + tile max ----
                const bool diag = (kvbase + 63 > qw);
                float tmax[2] = {-INFINITY, -INFINITY};
#pragma unroll
                for (int n = 0; n < 2; n++) {
                    int q = qw + li + 16 * n;
#pragma unroll
                    for (int m = 0; m < 4; m++) {
#pragma unroll
                        for (int r = 0; r < 4; r++) {
                            if (diag) {
                                int kv = kvbase + 16 * m + 4 * g + r;
                                if (kv > q) s[m][n][r] = -INFINITY;
                            }
                            tmax[n] = fmaxf(tmax[n], s[m][n][r]);
                        }
                    }
                }
                float corr[2];
#pragma unroll
                for (int n = 0; n < 2; n++) {
                    tmax[n] = fmaxf(tmax[n], __shfl_xor(tmax[n], 16));
                    tmax[n] = fmaxf(tmax[n], __shfl_xor(tmax[n], 32));
                    float mnew = fmaxf(mrow[n], tmax[n]);
                    corr[n] = __builtin_amdgcn_exp2f(mrow[n] - mnew);
                    mrow[n] = mnew;
                }
                // ---- P = exp2(S-m), pack P^T to LDS (swizzled), row sums ----
                float tsum[2] = {0.f, 0.f};
#pragma unroll
                for (int m = 0; m < 4; m++) {
#pragma unroll
                    for (int n = 0; n < 2; n++) {
                        float p0 = __builtin_amdgcn_exp2f(s[m][n][0] - mrow[n]);
                        float p1 = __builtin_amdgcn_exp2f(s[m][n][1] - mrow[n]);
                        float p2 = __builtin_amdgcn_exp2f(s[m][n][2] - mrow[n]);
                        float p3 = __builtin_amdgcn_exp2f(s[m][n][3] - mrow[n]);
                        tsum[n] += (p0 + p1) + (p2 + p3);
                        short4v pk;
                        pk[0] = f2bf(p0); pk[1] = f2bf(p1);
                        pk[2] = f2bf(p2); pk[3] = f2bf(p3);
                        *reinterpret_cast<short4v*>(
                            &Plds[w][li + 16 * n]
                                 [((2 * m + (g >> 1)) ^ sw) * 8 + (g & 1) * 4]) = pk;
                    }
                }
#pragma unroll
                for (int n = 0; n < 2; n++) {
                    tsum[n] += __shfl_xor(tsum[n], 16);
                    tsum[n] += __shfl_xor(tsum[n], 32);
                    lrow[n] = lrow[n] * corr[n] + tsum[n];
                }
                // ---- O rescale (skipped when max unchanged across wave) ----
                bool nore = (corr[0] == 1.0f) && (corr[1] == 1.0f);
                if (!__all((int)nore)) {
#pragma unroll
                    for (int df = 0; df < 4; df++)
#pragma unroll
                        for (int n = 0; n < 2; n++) {
                            accO[df][n][0] *= corr[n]; accO[df][n][1] *= corr[n];
                            accO[df][n][2] *= corr[n]; accO[df][n][3] *= corr[n];
                        }
                }
                // ---- O^T += V^T·P^T ----
#pragma unroll
                for (int ks = 0; ks < 2; ks++) {
                    short8 av[4], bp[2];
#pragma unroll
                    for (int df = 0; df < 4; df++)
                        av[df] = *reinterpret_cast<const short8*>(
                            &Vlds[buf][li + 16 * df][((ks * 4 + g) ^ sw) * 8]);
#pragma unroll
                    for (int n = 0; n < 2; n++)
                        bp[n] = *reinterpret_cast<const short8*>(
                            &Plds[w][li + 16 * n][((ks * 4 + g) ^ sw) * 8]);
#pragma unroll
                    for (int df = 0; df < 4; df++)
#pragma unroll
                        for (int n = 0; n < 2; n++)
                            accO[df][n] = __builtin_amdgcn_mfma_f32_16x16x32_bf16(
                                av[df], bp[n], accO[df][n], 0, 0, 0);
                }
            }

            if (more) {   // write next tile to the other buffer (waits on vmcnt here)
                const int nbuf = buf ^ 1;
                *reinterpret_cast<short8*>(&Klds[nbuf][c0r][(c0c ^ (c0r & 7)) * 8]) = kreg0;
                *reinterpret_cast<short8*>(&Vlds[nbuf][c0r][(c0c ^ (c0r & 7)) * 8]) = vreg0;
                *reinterpret_cast<short8*>(&Klds[nbuf][c1r][(c1c ^ (c1r & 7)) * 8]) = kreg1;
                *reinterpret_cast<short8*>(&Vlds[nbuf][c1r][(c1c ^ (c1r & 7)) * 8]) = vreg1;
            }
            __syncthreads();
        }

        // epilogue: O[q][d] = accO^T / l
#pragma unroll
        for (int n = 0; n < 2; n++) {
            float inv = 1.0f / lrow[n];
            int q = qw + li + 16 * n;
            size_t rowoff = (size_t)(b * SEQ + q) * DIMC + h * HDIM;
#pragma unroll
            for (int df = 0; df < 4; df++) {
                short4v pk;
#pragma unroll
                for (int r = 0; r < 4; r++) pk[r] = f2bf(accO[df][n][r] * inv);
                *reinterpret_cast<short4v*>(&og[rowoff + 16 * df + 4 * g]) = pk;
            }
        }
        __syncthreads();   // protect LDS before next pass's prologue writes
    }
}

extern "C" void kernel_launch(void* const* d_in, const int* in_sizes, int n_in,
                              void* d_out, int out_size, void* d_ws, size_t ws_size,
                              hipStream_t stream) {
    const float* x      = (const float*)d_in[0];   // [4,2048,1024]
    const float* w_qkv  = (const float*)d_in[1];   // [1024,3072]
    const float* w_proj = (const float*)d_in[2];   // [1024,1024]
    const float* b_proj = (const float*)d_in[3];   // [1024]
    float* out = (float*)d_out;                    // [4,2048,1024] fp32

    char* w = (char*)d_ws;
    unsigned short* qb  = (unsigned short*)(w);                        // 16 MB
    unsigned short* kb  = (unsigned short*)(w + ((size_t)16 << 20));   // 16 MB
    unsigned short* vtb = (unsigned short*)(w + ((size_t)32 << 20));   // 16 MB [B,H,D,S]
    unsigned short* ao  = (unsigned short*)(w + ((size_t)48 << 20));   // 16 MB
    unsigned short* wqt = (unsigned short*)(w + ((size_t)64 << 20));   // 6 MB
    unsigned short* wpt = (unsigned short*)(w + ((size_t)72 << 20));   // 2 MB
    unsigned short* xbf = (unsigned short*)(w + ((size_t)80 << 20));   // 16 MB

    xcvt<<<NROWS * DIMC / (256 * 8), 256, 0, stream>>>(x, xbf);
    transpose_cvt<<<dim3(3 * DIMC / 64, DIMC / 64), 256, 0, stream>>>(w_qkv, wqt, 3 * DIMC);
    transpose_cvt<<<dim3(DIMC / 64, DIMC / 64), 256, 0, stream>>>(w_proj, wpt, DIMC);
    qkv_gemm_mfma<<<dim3(3 * DIMC / 128, NROWS / 128), 256, 0, stream>>>(xbf, wqt, qb, kb, vtb);
    flash_attn_mfma<<<dim3(SEQ / 256, BATCH * NHEADS), 256, 0, stream>>>(qb, kb, vtb, ao);
    proj_gemm_mfma<<<dim3(DIMC / 128, NROWS / 128), 256, 0, stream>>>(ao, wpt, b_proj, out);
}

// Round 6
// 272.031 us; speedup vs baseline: 6.9096x; 1.1282x over previous
//
#include <hip/hip_runtime.h>
#include <hip/hip_bf16.h>
#include <math.h>

#define DIMC 1024
#define NHEADS 16
#define HDIM 64
#define BATCH 4
#define SEQ 2048
#define NROWS (BATCH * SEQ)      // 8192
#define ATTN_SCALE 0.125f        // 64^-0.5
#define LOG2E 1.4426950408889634f

typedef __attribute__((ext_vector_type(8))) short short8;   // 8 bf16 = 4 VGPR
typedef __attribute__((ext_vector_type(4))) short short4v;  // 4 bf16 = 2 VGPR
typedef __attribute__((ext_vector_type(4))) float f32x4;    // MFMA C/D

static __device__ __forceinline__ short f2bf(float f) {
    __hip_bfloat16 h = __float2bfloat16(f);
    return *reinterpret_cast<short*>(&h);
}

// async global->LDS, 16B per lane; LDS dest = wave-uniform base + lane*16
static __device__ __forceinline__ void gload16(const void* g, void* l) {
    __builtin_amdgcn_global_load_lds(
        (const __attribute__((address_space(1))) unsigned int*)g,
        (__attribute__((address_space(3))) unsigned int*)l, 16, 0, 0);
}

// ---------------------------------------------------------------------------
// X fp32 -> bf16 (row-major copy), 8 elems/thread
// ---------------------------------------------------------------------------
__global__ __launch_bounds__(256)
void xcvt(const float* __restrict__ in, unsigned short* __restrict__ out) {
    int i = blockIdx.x * 256 + threadIdx.x;
    const float4* p = reinterpret_cast<const float4*>(in) + 2 * i;
    float4 a = p[0], b = p[1];
    short8 pk;
    pk[0] = f2bf(a.x); pk[1] = f2bf(a.y); pk[2] = f2bf(a.z); pk[3] = f2bf(a.w);
    pk[4] = f2bf(b.x); pk[5] = f2bf(b.y); pk[6] = f2bf(b.z); pk[7] = f2bf(b.w);
    reinterpret_cast<short8*>(out)[i] = pk;
}

// ---------------------------------------------------------------------------
// transpose + fp32->bf16: src fp32 [1024][N] -> dst bf16 [N][1024]
// ---------------------------------------------------------------------------
__global__ __launch_bounds__(256)
void transpose_cvt(const float* __restrict__ src, unsigned short* __restrict__ dst,
                   int N) {
    __shared__ float t[64][65];
    const int tid = threadIdx.x;
    const int cb = blockIdx.x * 64;
    const int rb = blockIdx.y * 64;
#pragma unroll
    for (int e = 0; e < 4; e++) {
        int idx = tid + e * 256;
        int row = idx >> 4;
        int c4 = (idx & 15) << 2;
        *reinterpret_cast<float4*>(&t[row][c4]) =
            *reinterpret_cast<const float4*>(&src[(size_t)(rb + row) * N + cb + c4]);
    }
    __syncthreads();
#pragma unroll
    for (int e = 0; e < 2; e++) {
        int idx = tid + e * 256;
        int col = idx >> 3;
        int k8 = (idx & 7) << 3;
        short8 pk;
#pragma unroll
        for (int j = 0; j < 8; j++) pk[j] = f2bf(t[k8 + j][col]);
        *reinterpret_cast<short8*>(&dst[(size_t)(cb + col) * 1024 + rb + k8]) = pk;
    }
}

// ---------------------------------------------------------------------------
// qkv: Xbf bf16 [8192][1024] x Wt bf16 [3072][1024] -> bf16 q,k [B,H,S,D], vt [B,H,D,S]
// global_load_lds staging (m97 structure), LDS linear [128][32]
// q pre-scaled by ATTN_SCALE*LOG2E (softmax runs in exp2 domain)
// ---------------------------------------------------------------------------
__global__ __launch_bounds__(256)
void qkv_gemm_mfma(const unsigned short* __restrict__ Xbf,
                   const unsigned short* __restrict__ Wt,
                   unsigned short* __restrict__ qo, unsigned short* __restrict__ ko,
                   unsigned short* __restrict__ vt) {
    __shared__ short Alds[128][32];   // 8 KB, [row][k] bf16
    __shared__ short Blds[128][32];   // 8 KB, [col][k] bf16
    const int tid = threadIdx.x;
    const int lane = tid & 63;
    const int wave = tid >> 6;
    const int wr = wave >> 1, wc = wave & 1;
    const int rowbase = blockIdx.y * 128;
    const int colbase = blockIdx.x * 128;
    const int g = lane >> 4, li = lane & 15;
    // staging coords: chunk ch = ld*64+lane -> (row=ch>>2, cslot=ch&3)
    const int srow0 = (wave * 2 + 0) * 16 + (lane >> 2);
    const int srow1 = (wave * 2 + 1) * 16 + (lane >> 2);
    const int scol = (lane & 3) * 8;
    short* aflat = &Alds[0][0];
    short* bflat = &Blds[0][0];

    f32x4 acc[4][4];
#pragma unroll
    for (int m = 0; m < 4; m++)
#pragma unroll
        for (int n = 0; n < 4; n++) acc[m][n] = (f32x4){0.f, 0.f, 0.f, 0.f};

    for (int k0 = 0; k0 < DIMC; k0 += 32) {
        gload16(&Xbf[(size_t)(rowbase + srow0) * DIMC + k0 + scol],
                aflat + (wave * 2 + 0) * 512);
        gload16(&Xbf[(size_t)(rowbase + srow1) * DIMC + k0 + scol],
                aflat + (wave * 2 + 1) * 512);
        gload16(&Wt[(size_t)(colbase + srow0) * 1024 + k0 + scol],
                bflat + (wave * 2 + 0) * 512);
        gload16(&Wt[(size_t)(colbase + srow1) * 1024 + k0 + scol],
                bflat + (wave * 2 + 1) * 512);
        __syncthreads();
        short8 af[4], bfr[4];
#pragma unroll
        for (int m = 0; m < 4; m++)
            af[m] = *reinterpret_cast<const short8*>(&Alds[wr * 64 + m * 16 + li][g * 8]);
#pragma unroll
        for (int n = 0; n < 4; n++)
            bfr[n] = *reinterpret_cast<const short8*>(&Blds[wc * 64 + n * 16 + li][g * 8]);
#pragma unroll
        for (int m = 0; m < 4; m++)
#pragma unroll
            for (int n = 0; n < 4; n++)
                acc[m][n] = __builtin_amdgcn_mfma_f32_16x16x32_bf16(
                    af[m], bfr[n], acc[m][n], 0, 0, 0);
        __syncthreads();
    }

    const int col0 = colbase + wc * 64;
    const int three = col0 >> 10;
    const int h = (col0 & 1023) >> 6;
    if (three < 2) {
        unsigned short* dst = (three == 0) ? qo : ko;
        const float mult = (three == 0) ? (ATTN_SCALE * LOG2E) : 1.0f;
#pragma unroll
        for (int n = 0; n < 4; n++) {
            int d = n * 16 + li;
#pragma unroll
            for (int m = 0; m < 4; m++) {
                int r0 = rowbase + wr * 64 + m * 16 + g * 4;
                int b = r0 >> 11;
                size_t base = ((size_t)(b * NHEADS + h) * SEQ) * HDIM + d;
#pragma unroll
                for (int r = 0; r < 4; r++) {
                    int s = (r0 + r) & 2047;
                    dst[base + (size_t)s * HDIM] = (unsigned short)f2bf(acc[m][n][r] * mult);
                }
            }
        }
    } else {
        // v: store transposed [B,H,D,S]
#pragma unroll
        for (int n = 0; n < 4; n++) {
            int d = n * 16 + li;
#pragma unroll
            for (int m = 0; m < 4; m++) {
                int r0 = rowbase + wr * 64 + m * 16 + g * 4;
                int b = r0 >> 11, s0 = r0 & 2047;
                short4v pk;
#pragma unroll
                for (int r = 0; r < 4; r++) pk[r] = f2bf(acc[m][n][r]);
                *reinterpret_cast<short4v*>(
                    &vt[((size_t)(b * NHEADS + h) * HDIM + d) * SEQ + s0]) = pk;
            }
        }
    }
}

// ---------------------------------------------------------------------------
// proj: Abf bf16 [8192][1024] x Wt bf16 [1024][1024] + bias -> out fp32
// ---------------------------------------------------------------------------
__global__ __launch_bounds__(256)
void proj_gemm_mfma(const unsigned short* __restrict__ Abf,
                    const unsigned short* __restrict__ Wt,
                    const float* __restrict__ bias, float* __restrict__ out) {
    __shared__ short Alds[128][32];
    __shared__ short Blds[128][32];
    const int tid = threadIdx.x;
    const int lane = tid & 63;
    const int wave = tid >> 6;
    const int wr = wave >> 1, wc = wave & 1;
    const int rowbase = blockIdx.y * 128;
    const int colbase = blockIdx.x * 128;
    const int g = lane >> 4, li = lane & 15;
    const int srow0 = (wave * 2 + 0) * 16 + (lane >> 2);
    const int srow1 = (wave * 2 + 1) * 16 + (lane >> 2);
    const int scol = (lane & 3) * 8;
    short* aflat = &Alds[0][0];
    short* bflat = &Blds[0][0];

    f32x4 acc[4][4];
#pragma unroll
    for (int m = 0; m < 4; m++)
#pragma unroll
        for (int n = 0; n < 4; n++) acc[m][n] = (f32x4){0.f, 0.f, 0.f, 0.f};

    for (int k0 = 0; k0 < DIMC; k0 += 32) {
        gload16(&Abf[(size_t)(rowbase + srow0) * DIMC + k0 + scol],
                aflat + (wave * 2 + 0) * 512);
        gload16(&Abf[(size_t)(rowbase + srow1) * DIMC + k0 + scol],
                aflat + (wave * 2 + 1) * 512);
        gload16(&Wt[(size_t)(colbase + srow0) * 1024 + k0 + scol],
                bflat + (wave * 2 + 0) * 512);
        gload16(&Wt[(size_t)(colbase + srow1) * 1024 + k0 + scol],
                bflat + (wave * 2 + 1) * 512);
        __syncthreads();
        short8 af[4], bfr[4];
#pragma unroll
        for (int m = 0; m < 4; m++)
            af[m] = *reinterpret_cast<const short8*>(&Alds[wr * 64 + m * 16 + li][g * 8]);
#pragma unroll
        for (int n = 0; n < 4; n++)
            bfr[n] = *reinterpret_cast<const short8*>(&Blds[wc * 64 + n * 16 + li][g * 8]);
#pragma unroll
        for (int m = 0; m < 4; m++)
#pragma unroll
            for (int n = 0; n < 4; n++)
                acc[m][n] = __builtin_amdgcn_mfma_f32_16x16x32_bf16(
                    af[m], bfr[n], acc[m][n], 0, 0, 0);
        __syncthreads();
    }

#pragma unroll
    for (int n = 0; n < 4; n++) {
        int col = colbase + wc * 64 + n * 16 + li;
        float bv = bias[col];
#pragma unroll
        for (int m = 0; m < 4; m++) {
            int r0 = rowbase + wr * 64 + m * 16 + g * 4;
#pragma unroll
            for (int r = 0; r < 4; r++)
                out[(size_t)(r0 + r) * DIMC + col] = acc[m][n][r] + bv;
        }
    }
}

// ---------------------------------------------------------------------------
// MFMA flash attention (causal), exp2-domain softmax.
//  - 1D grid with bijective XCD swizzle: each XCD owns 8 whole heads ->
//    all 8 q-blocks of a head share one L2 (K/V re-reads become L2 hits)
//  - coalesced K/V staging, double-buffered, loads issued before compute
//  - balanced causal pairing: block handles q-tiles {x, 15-x}
// ---------------------------------------------------------------------------
__global__ __launch_bounds__(256)
void flash_attn_mfma(const unsigned short* __restrict__ qg,
                     const unsigned short* __restrict__ kg,
                     const unsigned short* __restrict__ vt,
                     unsigned short* __restrict__ og) {
    __shared__ short Klds[2][64][64];
    __shared__ short Vlds[2][64][64];
    __shared__ short Plds[4][32][64];
    const int tid = threadIdx.x;
    const int lane = tid & 63;
    const int w = tid >> 6;
    const int g = lane >> 4, li = lane & 15;
    const int sw = li & 7;
    // XCD-bijective swizzle: orig%8 = XCD (round-robin dispatch); group 64
    // consecutive swz-ids (8 heads x 8 q-blocks) onto one XCD.
    const int orig = blockIdx.x;                   // 0..511
    const int swz = (orig & 7) * 64 + (orig >> 3);
    const int bx = swz & 7;                        // q-block pair index
    const int bh = swz >> 3;                       // head 0..63
    const size_t head = (size_t)bh * SEQ * HDIM;
    const int b = bh >> 4, h = bh & 15;

    const int c0r = tid >> 3, c0c = tid & 7;
    const int c1r = (tid + 256) >> 3, c1c = tid & 7;

    for (int pass = 0; pass < 2; pass++) {
        const int qtile = pass ? (15 - bx) : bx;
        const int qbase = qtile * 128;
        const int qw = qbase + w * 32;
        const int nt = 2 * qtile + 2;

        short8 bq[2][2];
#pragma unroll
        for (int n = 0; n < 2; n++)
#pragma unroll
            for (int ds = 0; ds < 2; ds++)
                bq[n][ds] = *reinterpret_cast<const short8*>(
                    &qg[head + (size_t)(qw + li + 16 * n) * HDIM + ds * 32 + g * 8]);

        f32x4 accO[4][2];
#pragma unroll
        for (int df = 0; df < 4; df++)
#pragma unroll
            for (int n = 0; n < 2; n++) accO[df][n] = (f32x4){0.f, 0.f, 0.f, 0.f};
        float mrow[2] = {-INFINITY, -INFINITY};
        float lrow[2] = {0.f, 0.f};

        short8 kreg0, kreg1, vreg0, vreg1;
        kreg0 = *reinterpret_cast<const short8*>(&kg[head + (size_t)c0r * HDIM + c0c * 8]);
        vreg0 = *reinterpret_cast<const short8*>(&vt[head + (size_t)c0r * SEQ + c0c * 8]);
        kreg1 = *reinterpret_cast<const short8*>(&kg[head + (size_t)c1r * HDIM + c1c * 8]);
        vreg1 = *reinterpret_cast<const short8*>(&vt[head + (size_t)c1r * SEQ + c1c * 8]);
        *reinterpret_cast<short8*>(&Klds[0][c0r][(c0c ^ (c0r & 7)) * 8]) = kreg0;
        *reinterpret_cast<short8*>(&Vlds[0][c0r][(c0c ^ (c0r & 7)) * 8]) = vreg0;
        *reinterpret_cast<short8*>(&Klds[0][c1r][(c1c ^ (c1r & 7)) * 8]) = kreg1;
        *reinterpret_cast<short8*>(&Vlds[0][c1r][(c1c ^ (c1r & 7)) * 8]) = vreg1;
        __syncthreads();

        for (int t = 0; t < nt; t++) {
            const int kvbase = t * 64;
            const int buf = t & 1;
            const bool more = (t + 1 < nt);
            if (more) {
                const int kb2 = kvbase + 64;
                kreg0 = *reinterpret_cast<const short8*>(
                    &kg[head + (size_t)(kb2 + c0r) * HDIM + c0c * 8]);
                vreg0 = *reinterpret_cast<const short8*>(
                    &vt[head + (size_t)c0r * SEQ + kb2 + c0c * 8]);
                kreg1 = *reinterpret_cast<const short8*>(
                    &kg[head + (size_t)(kb2 + c1r) * HDIM + c1c * 8]);
                vreg1 = *reinterpret_cast<const short8*>(
                    &vt[head + (size_t)c1r * SEQ + kb2 + c1c * 8]);
            }

            if (kvbase <= qw + 31) {
                f32x4 s[4][2];
#pragma unroll
                for (int m = 0; m < 4; m++)
#pragma unroll
                    for (int n = 0; n < 2; n++) s[m][n] = (f32x4){0.f, 0.f, 0.f, 0.f};
#pragma unroll
                for (int ds = 0; ds < 2; ds++) {
                    short8 ak[4];
#pragma unroll
                    for (int m = 0; m < 4; m++)
                        ak[m] = *reinterpret_cast<const short8*>(
                            &Klds[buf][li + 16 * m][(((ds * 4 + g) ^ sw)) * 8]);
#pragma unroll
                    for (int m = 0; m < 4; m++)
#pragma unroll
                        for (int n = 0; n < 2; n++)
                            s[m][n] = __builtin_amdgcn_mfma_f32_16x16x32_bf16(
                                ak[m], bq[n][ds], s[m][n], 0, 0, 0);
                }
                const bool diag = (kvbase + 63 > qw);
                float tmax[2] = {-INFINITY, -INFINITY};
#pragma unroll
                for (int n = 0; n < 2; n++) {
                    int q = qw + li + 16 * n;
#pragma unroll
                    for (int m = 0; m < 4; m++) {
#pragma unroll
                        for (int r = 0; r < 4; r++) {
                            if (diag) {
                                int kv = kvbase + 16 * m + 4 * g + r;
                                if (kv > q) s[m][n][r] = -INFINITY;
                            }
                            tmax[n] = fmaxf(tmax[n], s[m][n][r]);
                        }
                    }
                }
                float corr[2];
#pragma unroll
                for (int n = 0; n < 2; n++) {
                    tmax[n] = fmaxf(tmax[n], __shfl_xor(tmax[n], 16));
                    tmax[n] = fmaxf(tmax[n], __shfl_xor(tmax[n], 32));
                    float mnew = fmaxf(mrow[n], tmax[n]);
                    corr[n] = __builtin_amdgcn_exp2f(mrow[n] - mnew);
                    mrow[n] = mnew;
                }
                float tsum[2] = {0.f, 0.f};
#pragma unroll
                for (int m = 0; m < 4; m++) {
#pragma unroll
                    for (int n = 0; n < 2; n++) {
                        float p0 = __builtin_amdgcn_exp2f(s[m][n][0] - mrow[n]);
                        float p1 = __builtin_amdgcn_exp2f(s[m][n][1] - mrow[n]);
                        float p2 = __builtin_amdgcn_exp2f(s[m][n][2] - mrow[n]);
                        float p3 = __builtin_amdgcn_exp2f(s[m][n][3] - mrow[n]);
                        tsum[n] += (p0 + p1) + (p2 + p3);
                        short4v pk;
                        pk[0] = f2bf(p0); pk[1] = f2bf(p1);
                        pk[2] = f2bf(p2); pk[3] = f2bf(p3);
                        *reinterpret_cast<short4v*>(
                            &Plds[w][li + 16 * n]
                                 [((2 * m + (g >> 1)) ^ sw) * 8 + (g & 1) * 4]) = pk;
                    }
                }
#pragma unroll
                for (int n = 0; n < 2; n++) {
                    tsum[n] += __shfl_xor(tsum[n], 16);
                    tsum[n] += __shfl_xor(tsum[n], 32);
                    lrow[n] = lrow[n] * corr[n] + tsum[n];
                }
                bool nore = (corr[0] == 1.0f) && (corr[1] == 1.0f);
                if (!__all((int)nore)) {
#pragma unroll
                    for (int df = 0; df < 4; df++)
#pragma unroll
                        for (int n = 0; n < 2; n++) {
                            accO[df][n][0] *= corr[n]; accO[df][n][1] *= corr[n];
                            accO[df][n][2] *= corr[n]; accO[df][n][3] *= corr[n];
                        }
                }
#pragma unroll
                for (int ks = 0; ks < 2; ks++) {
                    short8 av[4], bp[2];
#pragma unroll
                    for (int df = 0; df < 4; df++)
                        av[df] = *reinterpret_cast<const short8*>(
                            &Vlds[buf][li + 16 * df][((ks * 4 + g) ^ sw) * 8]);
#pragma unroll
                    for (int n = 0; n < 2; n++)
                        bp[n] = *reinterpret_cast<const short8*>(
                            &Plds[w][li + 16 * n][((ks * 4 + g) ^ sw) * 8]);
#pragma unroll
                    for (int df = 0; df < 4; df++)
#pragma unroll
                        for (int n = 0; n < 2; n++)
                            accO[df][n] = __builtin_amdgcn_mfma_f32_16x16x32_bf16(
                                av[df], bp[n], accO[df][n], 0, 0, 0);
                }
            }

            if (more) {
                const int nbuf = buf ^ 1;
                *reinterpret_cast<short8*>(&Klds[nbuf][c0r][(c0c ^ (c0r & 7)) * 8]) = kreg0;
                *reinterpret_cast<short8*>(&Vlds[nbuf][c0r][(c0c ^ (c0r & 7)) * 8]) = vreg0;
                *reinterpret_cast<short8*>(&Klds[nbuf][c1r][(c1c ^ (c1r & 7)) * 8]) = kreg1;
                *reinterpret_cast<short8*>(&Vlds[nbuf][c1r][(c1c ^ (c1r & 7)) * 8]) = vreg1;
            }
            __syncthreads();
        }

#pragma unroll
        for (int n = 0; n < 2; n++) {
            float inv = 1.0f / lrow[n];
            int q = qw + li + 16 * n;
            size_t rowoff = (size_t)(b * SEQ + q) * DIMC + h * HDIM;
#pragma unroll
            for (int df = 0; df < 4; df++) {
                short4v pk;
#pragma unroll
                for (int r = 0; r < 4; r++) pk[r] = f2bf(accO[df][n][r] * inv);
                *reinterpret_cast<short4v*>(&og[rowoff + 16 * df + 4 * g]) = pk;
            }
        }
        __syncthreads();
    }
}

extern "C" void kernel_launch(void* const* d_in, const int* in_sizes, int n_in,
                              void* d_out, int out_size, void* d_ws, size_t ws_size,
                              hipStream_t stream) {
    const float* x      = (const float*)d_in[0];   // [4,2048,1024]
    const float* w_qkv  = (const float*)d_in[1];   // [1024,3072]
    const float* w_proj = (const float*)d_in[2];   // [1024,1024]
    const float* b_proj = (const float*)d_in[3];   // [1024]
    float* out = (float*)d_out;                    // [4,2048,1024] fp32

    char* w = (char*)d_ws;
    unsigned short* qb  = (unsigned short*)(w);                        // 16 MB
    unsigned short* kb  = (unsigned short*)(w + ((size_t)16 << 20));   // 16 MB
    unsigned short* vtb = (unsigned short*)(w + ((size_t)32 << 20));   // 16 MB [B,H,D,S]
    unsigned short* ao  = (unsigned short*)(w + ((size_t)48 << 20));   // 16 MB
    unsigned short* wqt = (unsigned short*)(w + ((size_t)64 << 20));   // 6 MB
    unsigned short* wpt = (unsigned short*)(w + ((size_t)72 << 20));   // 2 MB
    unsigned short* xbf = (unsigned short*)(w + ((size_t)80 << 20));   // 16 MB

    xcvt<<<NROWS * DIMC / (256 * 8), 256, 0, stream>>>(x, xbf);
    transpose_cvt<<<dim3(3 * DIMC / 64, DIMC / 64), 256, 0, stream>>>(w_qkv, wqt, 3 * DIMC);
    transpose_cvt<<<dim3(DIMC / 64, DIMC / 64), 256, 0, stream>>>(w_proj, wpt, DIMC);
    qkv_gemm_mfma<<<dim3(3 * DIMC / 128, NROWS / 128), 256, 0, stream>>>(xbf, wqt, qb, kb, vtb);
    flash_attn_mfma<<<512, 256, 0, stream>>>(qb, kb, vtb, ao);
    proj_gemm_mfma<<<dim3(DIMC / 128, NROWS / 128), 256, 0, stream>>>(ao, wpt, b_proj, out);
}